// Round 5
// baseline (3447.606 us; speedup 1.0000x reference)
//
#include <hip/hip_runtime.h>
#include <math.h>

#define DI __device__ __forceinline__

DI float sigm(float x){ return 1.0f/(1.0f+expf(-x)); }
DI float lrelu(float x){ return x > 0.f ? x : 0.01f*x; }

template<int ACT>
DI float act_apply(float v){
    if (ACT == 1) return tanhf(v);
    if (ACT == 2) return lrelu(v);
    return v;
}

// ---------------- encoder conv: stride 2, 4x4, tanh ----------------
template<int CIN, int COUT>
__global__ __launch_bounds__(256)
void conv_enc_kernel(const float* __restrict__ in, const float* __restrict__ w,
                     const float* __restrict__ bias, float* __restrict__ out,
                     int N, int H, int OH)
{
    int idx = blockIdx.x*256 + threadIdx.x;
    int total = N*COUT*OH*OH;
    if (idx >= total) return;
    int ox = idx % OH; int t = idx / OH;
    int oy = t % OH;   t /= OH;
    int o  = t % COUT; int n = t / COUT;
    float acc = bias[o];
    const float* wp = w + o*CIN*16;
    const float* ip = in + ((size_t)n*CIN)*H*H + (oy*2)*H + ox*2;
    for (int c = 0; c < CIN; ++c) {
        const float* ipc = ip + c*H*H;
        const float* wpc = wp + c*16;
        #pragma unroll
        for (int ky = 0; ky < 4; ++ky)
            #pragma unroll
            for (int kx = 0; kx < 4; ++kx)
                acc = fmaf(ipc[ky*H + kx], wpc[ky*4 + kx], acc);
    }
    out[idx] = tanhf(acc);
}

// ---------------- tiled GEMM: C = act(A @ op(B) + bias), optional split-K ----
template<int BM,int BN,int BK,bool BT,int ACT>
__global__ __launch_bounds__((BM/4)*(BN/4))
void gemm_kernel(const float* __restrict__ A, const float* __restrict__ Bm,
                 const float* __restrict__ bias, float* __restrict__ C,
                 int M, int N, int Kfull, int klen, int ldc, int bias_div,
                 long partStride)
{
    constexpr int TM = 4, TN = 4;
    constexpr int THREADS = (BM/TM)*(BN/TN);
    constexpr int LDA = BM + 4, LDB = BN + 4;
    __shared__ __align__(16) float As[BK][LDA];
    __shared__ __align__(16) float Bs[BK][LDB];
    int tid = threadIdx.x;
    int m0 = blockIdx.y * BM, n0 = blockIdx.x * BN;
    int koff = blockIdx.z * klen;
    C += (long)blockIdx.z * partStride;
    constexpr int NTX = BN/TN;
    int tx = tid % NTX, ty = tid / NTX;
    float acc[4][4];
    #pragma unroll
    for (int i=0;i<4;++i)
        #pragma unroll
        for (int j=0;j<4;++j) acc[i][j] = 0.f;

    for (int k0 = 0; k0 < klen; k0 += BK) {
        for (int e = tid; e < BM*BK; e += THREADS) {
            int k = e % BK, m = e / BK;
            As[k][m] = (m0+m < M) ? A[(size_t)(m0+m)*Kfull + koff + k0 + k] : 0.f;
        }
        if (BT) {
            for (int e = tid; e < BN*BK; e += THREADS) {
                int k = e % BK, n = e / BK;
                Bs[k][n] = (n0+n < N) ? Bm[(size_t)(n0+n)*Kfull + koff + k0 + k] : 0.f;
            }
        } else {
            for (int e = tid; e < BN*BK; e += THREADS) {
                int n = e % BN, k = e / BN;
                Bs[k][n] = (n0+n < N) ? Bm[(size_t)(koff + k0 + k)*N + n0+n] : 0.f;
            }
        }
        __syncthreads();
        #pragma unroll 8
        for (int k = 0; k < BK; ++k) {
            float4 a4 = *reinterpret_cast<const float4*>(&As[k][ty*4]);
            float4 b4 = *reinterpret_cast<const float4*>(&Bs[k][tx*4]);
            float av[4] = {a4.x, a4.y, a4.z, a4.w};
            float bv[4] = {b4.x, b4.y, b4.z, b4.w};
            #pragma unroll
            for (int i=0;i<4;++i)
                #pragma unroll
                for (int j=0;j<4;++j)
                    acc[i][j] = fmaf(av[i], bv[j], acc[i][j]);
        }
        __syncthreads();
    }
    #pragma unroll
    for (int i=0;i<4;++i) {
        int m = m0 + ty*4 + i;
        if (m >= M) continue;
        #pragma unroll
        for (int j=0;j<4;++j) {
            int n = n0 + tx*4 + j;
            if (n >= N) continue;
            float v = acc[i][j] + (bias ? bias[n / bias_div] : 0.f);
            C[(size_t)m*ldc + n] = act_apply<ACT>(v);
        }
    }
}

// ---------------- small helpers ----------------
__global__ __launch_bounds__(256)
void addvec_kernel(const float* __restrict__ a, const float* __restrict__ b,
                   float* __restrict__ o, int n)
{
    int i = blockIdx.x*256 + threadIdx.x;
    if (i < n) o[i] = a[i] + b[i];
}

__global__ __launch_bounds__(64)
void concat_action_kernel(const float* __restrict__ action, float* __restrict__ z)
{
    int i = blockIdx.x*64 + threadIdx.x;
    if (i < 50*30) { int b = i/30, k = i%30; z[b*512 + 482 + k] = action[i]; }
}

__global__ __launch_bounds__(64)
void reward_kernel(const float* __restrict__ z, const float* __restrict__ w,
                   const float* __restrict__ b, float* __restrict__ out)
{
    int bi = threadIdx.x;
    if (bi < 50) {
        float acc = b[0];
        for (int k = 0; k < 512; ++k) acc = fmaf(z[bi*512 + k], w[k], acc);
        out[bi] = acc;
    }
}

// gates from 8 split-K partial buffers + combined bias
__global__ __launch_bounds__(256)
void lstm_gates8_kernel(const float* __restrict__ gp, const float* __restrict__ bsum,
                        const float* __restrict__ c_prev,
                        float* __restrict__ c_out, float* __restrict__ h_out,
                        float* __restrict__ outs_t)
{
    int idx = blockIdx.x*256 + threadIdx.x;
    if (idx >= 50*1024) return;
    int b = idx >> 10, j = idx & 1023;
    float s0 = bsum[j], s1 = bsum[1024+j], s2 = bsum[2048+j], s3 = bsum[3072+j];
    #pragma unroll
    for (int p = 0; p < 8; ++p) {
        const float* base = gp + (size_t)p*204800 + b*4096 + j;
        s0 += base[0]; s1 += base[1024]; s2 += base[2048]; s3 += base[3072];
    }
    float cp = c_prev[idx];
    float c = sigm(s1)*cp + sigm(s0)*tanhf(s2);
    float h = sigm(s3)*tanhf(c);
    c_out[idx] = c; h_out[idx] = h; outs_t[idx] = h;
}

// ---------------- weight prep for parity-decomposed deconv ----------------
// wp[((pp*CIN + c)*COUT + o)*12 + j*4 + i] = w[c][o][py+2j][px+2i] (0 pad), pp=py*2+px
__global__ __launch_bounds__(256)
void wprep_kernel(const float* __restrict__ w, float* __restrict__ wp,
                  int CIN, int COUT, int KS)
{
    int idx = blockIdx.x*256 + threadIdx.x;
    int total = 4*CIN*COUT*12;
    if (idx >= total) return;
    int slot = idx % 12; int rem = idx / 12;
    int o = rem % COUT; rem /= COUT;
    int c = rem % CIN;  int pp = rem / CIN;
    int py = pp >> 1, px = pp & 1;
    int j = slot >> 2, i = slot & 3;
    int ky = py + 2*j, kx = px + 2*i;
    float v = 0.f;
    if (i < 3 && ky < KS && kx < KS)
        v = w[(((size_t)c*COUT + o)*KS + ky)*KS + kx];
    wp[idx] = v;
}

// ---------------- parity-merged transposed conv, v-split blocks -------------
// Block = (n, seg). ISTR/OSTR = padded row strides of input/output buffers.
// Task = (vi, o, tb): VPER v's (v = v0+vi+q*NVB), 2-row x 2*TWU patch at u0.
template<int CIN,int COUT,int HIN,int HOUT,int ACT,int VSPLIT,int ROWP,int TWU,
         int VPER,int TB,int MWAVES,int ISTR,int OSTR>
__global__ __launch_bounds__(256, MWAVES)
void deconv4_kernel(const float* __restrict__ in, const float* __restrict__ wp,
                    const float* __restrict__ bias, float* __restrict__ out)
{
    constexpr int NV = (HOUT + 1) / 2;
    constexpr int NVSEG = (NV + VSPLIT - 1) / VSPLIT;
    constexpr int NVB = (NVSEG + VPER - 1) / VPER;
    constexpr int ROWS_MAX = (NVSEG + 2 < HIN) ? (NVSEG + 2) : HIN;
    constexpr int NR4 = (TWU + 2 + 3) / 4;
    constexpr int RLEN = (TWU == 1) ? 4 : NR4*4;
    static_assert(NVB * COUT * TB <= 256, "tasks must fit one per thread");
    __shared__ __align__(16) float slab[CIN*ROWS_MAX*ROWP];

    int n   = blockIdx.x / VSPLIT;
    int seg = blockIdx.x % VSPLIT;
    int v0 = seg * NVSEG;
    int v1 = (v0 + NVSEG < NV) ? v0 + NVSEG : NV;
    int r0 = (v0 - 2 > 0) ? v0 - 2 : 0;
    int r1m = (v1 - 1 < HIN - 1) ? v1 - 1 : HIN - 1;
    int nrows = r1m - r0 + 1;
    int tid = threadIdx.x;
    const float* inb = in + (size_t)n*CIN*HIN*ISTR;
    const size_t PPSTR = (size_t)CIN*COUT*12;

    // stage slab (rows zero-padded: [0,1]=0, [2..HIN+1]=data, rest 0)
    for (int e = tid; e < CIN*ROWS_MAX; e += 256) {
        int c = e / ROWS_MAX, ri = e % ROWS_MAX;
        if (ri < nrows) {
            const float* src = inb + ((size_t)c*HIN + r0 + ri)*ISTR;
            float* dst = slab + (c*ROWS_MAX + ri)*ROWP;
            dst[0] = 0.f; dst[1] = 0.f;
            #pragma unroll
            for (int x2 = HIN+2; x2 < ROWP; ++x2) dst[x2] = 0.f;
            for (int x2 = 0; x2 < HIN; ++x2) dst[2+x2] = src[x2];
        }
    }
    __syncthreads();

    int task = tid;
    int vi = task % NVB; int rem = task / NVB;
    int o = rem % COUT;  int tb = rem / COUT;
    int u0 = tb * TWU;
    bool anyv = false;
    int vg[VPER];
    #pragma unroll
    for (int q = 0; q < VPER; ++q) {
        vg[q] = v0 + vi + q*NVB;
        if (vg[q] < v1) anyv = true;
    }
    if (tb >= TB) anyv = false;

    float acc[VPER][2][2][TWU];
    #pragma unroll
    for (int q=0;q<VPER;++q)
        #pragma unroll
        for (int a=0;a<2;++a)
            #pragma unroll
            for (int b=0;b<2;++b)
                #pragma unroll
                for (int t=0;t<TWU;++t) acc[q][a][b][t] = 0.f;

    if (anyv) {
        const float* wb0 = wp + (size_t)o*12;
        for (int c = 0; c < CIN; ++c) {
            const float* wbase = wb0 + (size_t)c*COUT*12;
            const float* sc = slab + c*(ROWS_MAX*ROWP);
            #pragma unroll
            for (int jj = 0; jj < 3; ++jj) {
                float r[VPER][RLEN];
                #pragma unroll
                for (int q = 0; q < VPER; ++q) {
                    int iy = vg[q] - jj;
                    if (iy >= 0 && iy < HIN) {
                        const float* srow = sc + (iy - r0)*ROWP + u0;
                        if constexpr (TWU == 1) {
                            r[q][0] = srow[0]; r[q][1] = srow[1]; r[q][2] = srow[2];
                        } else {
                            #pragma unroll
                            for (int p4 = 0; p4 < NR4; ++p4) {
                                float4 f = *reinterpret_cast<const float4*>(srow + p4*4);
                                r[q][p4*4]=f.x; r[q][p4*4+1]=f.y; r[q][p4*4+2]=f.z; r[q][p4*4+3]=f.w;
                            }
                        }
                    } else {
                        #pragma unroll
                        for (int p4 = 0; p4 < RLEN; ++p4) r[q][p4] = 0.f;
                    }
                }
                #pragma unroll
                for (int pp = 0; pp < 4; ++pp) {
                    float4 w4 = *reinterpret_cast<const float4*>(wbase + pp*PPSTR + jj*4);
                    int py = pp >> 1, px = pp & 1;
                    #pragma unroll
                    for (int q = 0; q < VPER; ++q)
                        #pragma unroll
                        for (int t = 0; t < TWU; ++t)
                            acc[q][py][px][t] =
                                fmaf(w4.x, r[q][t+2],
                                fmaf(w4.y, r[q][t+1],
                                fmaf(w4.z, r[q][t], acc[q][py][px][t])));
                }
            }
        }
        // store
        float bv = bias[o];
        #pragma unroll
        for (int q = 0; q < VPER; ++q) {
            if (vg[q] >= v1) continue;
            #pragma unroll
            for (int py = 0; py < 2; ++py) {
                int y = py + 2*vg[q];
                if (y >= HOUT) continue;
                float* ob = out + (((size_t)n*COUT + o)*HOUT + y)*OSTR;
                #pragma unroll
                for (int t = 0; t < TWU; ++t) {
                    int x0 = 2*(u0+t);
                    if (x0 + 1 < HOUT) {
                        float2 qv;
                        qv.x = act_apply<ACT>(acc[q][py][0][t] + bv);
                        qv.y = act_apply<ACT>(acc[q][py][1][t] + bv);
                        *reinterpret_cast<float2*>(ob + x0) = qv;
                    } else if (x0 < HOUT) {
                        ob[x0] = act_apply<ACT>(acc[q][py][0][t] + bv);
                    }
                }
            }
        }
    }
}

// ---------------- launch ----------------
extern "C" void kernel_launch(void* const* d_in, const int* in_sizes, int n_in,
                              void* d_out, int out_size, void* d_ws, size_t ws_size,
                              hipStream_t stream)
{
    const float* x       = (const float*)d_in[0];
    const float* action  = (const float*)d_in[1];
    const float* h0      = (const float*)d_in[2];
    const float* c0      = (const float*)d_in[3];
    const float* conv1_w = (const float*)d_in[4];  const float* conv1_b = (const float*)d_in[5];
    const float* conv2_w = (const float*)d_in[6];  const float* conv2_b = (const float*)d_in[7];
    const float* conv3_w = (const float*)d_in[8];  const float* conv3_b = (const float*)d_in[9];
    const float* conv4_w = (const float*)d_in[10]; const float* conv4_b = (const float*)d_in[11];
    const float* fc1_w   = (const float*)d_in[12]; const float* fc1_b   = (const float*)d_in[13];
    const float* fc2_w   = (const float*)d_in[14]; const float* fc2_b   = (const float*)d_in[15];
    const float* w_ih    = (const float*)d_in[16]; const float* w_hh    = (const float*)d_in[17];
    const float* b_ih    = (const float*)d_in[18]; const float* b_hh    = (const float*)d_in[19];
    const float* fcsd_w  = (const float*)d_in[20]; const float* fcsd_b  = (const float*)d_in[21];
    const float* d1_w    = (const float*)d_in[22]; const float* d1_b    = (const float*)d_in[23];
    const float* d2_w    = (const float*)d_in[24]; const float* d2_b    = (const float*)d_in[25];
    const float* d3_w    = (const float*)d_in[26]; const float* d3_b    = (const float*)d_in[27];
    const float* d4_w    = (const float*)d_in[28]; const float* d4_b    = (const float*)d_in[29];
    const float* fc5_w   = (const float*)d_in[30]; const float* fc5_b   = (const float*)d_in[31];
    float* out = (float*)d_out;
    float* ws  = (float*)d_ws;

    // workspace layout (floats); y2/y3 rows padded to 16/32 for aligned stores
    float* a1   = ws;                 // 1,537,600  [50,32,31,31]
    float* a2   = a1 + 1537600;       //   627,200  [50,64,14,14]
    float* a3   = a2 + 627200;        //   230,400  [50,128,6,6]
    float* flat = a3 + 230400;        //    51,200  [50,1024]
    float* z    = flat + 51200;       //    25,600  [50,512]
    float* fc2o = z + 25600;          //    51,200  [50,1024]
    float* hbuf = fc2o + 51200;       //    51,200
    float* cbuf = hbuf + 51200;       //    51,200
    float* outs = cbuf + 51200;       //   870,400  [17,50,1024]
    float* hd   = outs + 870400;      //   870,400  [850,1024]
    float* wsum = hd + 870400;        // 4,194,304
    float* bsum = wsum + 4194304;     //     4,096
    float* wp2  = bsum + 4096;        //   393,216
    float* wp3  = wp2 + 393216;       //    98,304
    float* wp4  = wp3 + 98304;        //     1,536
    float* y1   = wp4 + 1536;         //  2,720,000  [850,128,5,5]
    float* y2   = y1 + 2720000;       // 11,315,200  [850,64,13,16] padded
    float* y3   = y2 + 11315200;      // 26,112,000  [850,32,30,32] padded
    float* g8   = y1;                 // 8*204,800 floats; y1/y2 dead during LSTM

    const int B = 50;
    const long GP = 204800;  // per-part stride in g8

    // prep
    addvec_kernel<<<(4194304+255)/256, 256, 0, stream>>>(w_ih, w_hh, wsum, 4194304);
    addvec_kernel<<<(4096+255)/256, 256, 0, stream>>>(b_ih, b_hh, bsum, 4096);
    wprep_kernel<<<(4*128*64*12+255)/256, 256, 0, stream>>>(d2_w, wp2, 128, 64, 5);
    wprep_kernel<<<(4*64*32*12+255)/256, 256, 0, stream>>>(d3_w, wp3, 64, 32, 6);
    wprep_kernel<<<(4*32*1*12+255)/256, 256, 0, stream>>>(d4_w, wp4, 32, 1, 6);

    // encoder
    conv_enc_kernel<1,32><<<(B*32*31*31+255)/256, 256, 0, stream>>>(x, conv1_w, conv1_b, a1, B, 64, 31);
    conv_enc_kernel<32,64><<<(B*64*14*14+255)/256, 256, 0, stream>>>(a1, conv2_w, conv2_b, a2, B, 31, 14);
    conv_enc_kernel<64,128><<<(B*128*6*6+255)/256, 256, 0, stream>>>(a2, conv3_w, conv3_b, a3, B, 14, 6);
    conv_enc_kernel<128,256><<<(B*256*2*2+255)/256, 256, 0, stream>>>(a3, conv4_w, conv4_b, flat, B, 6, 2);

    // fc1 -> z[:, :482]; action -> z[:, 482:512]; reward head
    {
        dim3 grid((482+63)/64, (B+31)/32, 1);
        gemm_kernel<32,64,32,true,0><<<grid, 128, 0, stream>>>(flat, fc1_w, fc1_b, z, B, 482, 1024, 1024, 512, 1, 0);
    }
    concat_action_kernel<<<(1500+63)/64, 64, 0, stream>>>(action, z);
    reward_kernel<<<1, 64, 0, stream>>>(z, fc5_w, fc5_b, out + (size_t)850*4096);

    // fc2 (leaky relu)
    {
        dim3 grid((1024+63)/64, (B+31)/32, 1);
        gemm_kernel<32,64,32,true,2><<<grid, 128, 0, stream>>>(z, fc2_w, fc2_b, fc2o, B, 1024, 512, 512, 1024, 1, 0);
    }

    // LSTM, 17 steps, split-K 8 partials in g8 (dead y1/y2 region)
    {
        dim3 grid0(64, 2, 4);
        gemm_kernel<32,64,32,true,0><<<grid0, 128, 0, stream>>>(fc2o, w_ih, nullptr, g8, B, 4096, 1024, 256, 4096, 1, GP);
        gemm_kernel<32,64,32,true,0><<<grid0, 128, 0, stream>>>(h0, w_hh, nullptr, g8 + 4*GP, B, 4096, 1024, 256, 4096, 1, GP);
        lstm_gates8_kernel<<<200, 256, 0, stream>>>(g8, bsum, c0, cbuf, hbuf, outs);
        dim3 gridt(64, 2, 8);
        for (int t = 1; t < 17; ++t) {
            gemm_kernel<32,64,32,true,0><<<gridt, 128, 0, stream>>>(hbuf, wsum, nullptr, g8, B, 4096, 1024, 128, 4096, 1, GP);
            lstm_gates8_kernel<<<200, 256, 0, stream>>>(g8, bsum, cbuf, cbuf, hbuf, outs + (size_t)t*51200);
        }
    }

    // fcsd: hd = leaky(outs @ fcsd_w^T + fcsd_b)   [850,1024]
    {
        dim3 grid((1024+63)/64, (850+63)/64, 1);
        gemm_kernel<64,64,32,true,2><<<grid, 256, 0, stream>>>(outs, fcsd_w, fcsd_b, hd, 850, 1024, 1024, 1024, 1024, 1, 0);
    }
    // d1: 1x1 spatial input -> pure GEMM [850,1024]x[1024,3200], tanh
    {
        dim3 grid((3200+63)/64, (850+63)/64, 1);
        gemm_kernel<64,64,32,false,1><<<grid, 256, 0, stream>>>(hd, d1_w, d1_b, y1, 850, 3200, 1024, 1024, 3200, 25, 0);
    }

    // d2: CIN=128,COUT=64,HIN=5,HOUT=13; VPER=2, TWU=7, slab 30.7KB (5 blk/CU)
    deconv4_kernel<128,64,5,13,1, 1,12,7,2,1,3, 5,16><<<850, 256, 0, stream>>>(y1, wp2, d2_b, y2);
    // d3: CIN=64,COUT=32,HIN=13,HOUT=30; v-split 2, VPER=2, TB=2, TWU=8
    deconv4_kernel<64,32,13,30,1, 2,20,8,2,2,3, 16,32><<<1700, 256, 0, stream>>>(y2, wp3, d3_b, y3);
    // d4: CIN=32,COUT=1,HIN=30,HOUT=64; v-split 4, TWU=1, TB=32
    deconv4_kernel<32,1,30,64,0, 4,36,1,1,32,3, 32,64><<<3400, 256, 0, stream>>>(y3, wp4, d4_b, out);

    (void)in_sizes; (void)n_in; (void)out_size; (void)ws_size;
}